// Round 14
// baseline (1518.138 us; speedup 1.0000x reference)
//
#include <hip/hip_runtime.h>
#include <cstdint>

#define N_IMG 8
#define CIN 512
#define COUT 256
#define FH 50
#define FW 50
#define SPAT 2500
#define NANCH 22500
#define KTOP 1000
#define PART_ELEMS 5120000   // 8*256*2500

// ---------------------------------------------------------------- K1: 3x3 SAME conv, fp64 accumulate, cin-split S parts
// R11/R13 measured optimum: block 256 = 64 oc x 4 groups(5x5); tile 10x10;
// grid (25 tiles, 4 ocg, 8*S). Per-element accumulation order (cc asc, c asc,
// tap asc) identical to R3..R13 -> bit-identical partials.
__global__ __launch_bounds__(256) void k_conv3_part(const float* __restrict__ in,
                                                    const float* __restrict__ w,
                                                    double* __restrict__ parts,
                                                    int S)
{
    __shared__ double ind[2][1152];   // [buf][c*144 + iy*12 + ix]  18,432 B

    const int tile = blockIdx.x, ocg = blockIdx.y;
    const int n = blockIdx.z / S, s = blockIdx.z - n * S;
    const int ccp = 64 / S;
    const int cc0 = s * ccp, cc1 = cc0 + ccp;
    const int ty = tile / 5, tx = tile % 5;
    const int y0 = ty * 10, x0 = tx * 10;
    const int t = threadIdx.x;
    const int oc_l = t & 63;
    const int g = t >> 6;                         // group 0..3
    const int base_ly = (g >> 1) * 5, base_lx = (g & 1) * 5;
    const int oc0 = ocg * 64;

    int soff[5];
#pragma unroll
    for (int k = 0; k < 5; k++) {
        int idx = t + k * 256;
        soff[k] = -1;
        if (idx < 1152) {
            int c = idx / 144, rem = idx - c * 144;
            int iy = rem / 12, ix = rem - iy * 12;
            int y = y0 - 1 + iy, x = x0 - 1 + ix;
            if ((unsigned)y < 50u && (unsigned)x < 50u)
                soff[k] = (n * CIN + c) * SPAT + y * FW + x;
        }
    }

    const float* wrow = w + (size_t)(oc0 + oc_l) * (CIN * 9);

    double acc[5][5];
#pragma unroll
    for (int i = 0; i < 5; i++)
#pragma unroll
        for (int j = 0; j < 5; j++) acc[i][j] = 0.0;

    float rin[5];
    {
        const int coff0 = cc0 * (8 * SPAT);
#pragma unroll
        for (int k = 0; k < 5; k++) rin[k] = (soff[k] >= 0) ? in[soff[k] + coff0] : 0.0f;
    }
    float wnxt[9];
    {
        const float* wp0 = wrow + cc0 * 72;
#pragma unroll
        for (int k = 0; k < 9; k++) wnxt[k] = wp0[k];
    }

    for (int cc = cc0; cc < cc1; ++cc) {
        const int cur = cc & 1;
#pragma unroll
        for (int k = 0; k < 5; k++) {
            int idx = t + k * 256;
            if (idx < 1152) ind[cur][idx] = (double)rin[k];
        }
        __syncthreads();

        if (cc + 1 < cc1) {
            const int coff = (cc + 1) * (8 * SPAT);
#pragma unroll
            for (int k = 0; k < 5; k++)
                rin[k] = (soff[k] >= 0) ? in[soff[k] + coff] : 0.0f;
        }

#pragma unroll 1
        for (int c = 0; c < 8; c++) {
            double wd[9];
#pragma unroll
            for (int k = 0; k < 9; k++) wd[k] = (double)wnxt[k];
            const int nidx = cc * 8 + c + 1;
            if (nidx < cc1 * 8) {
                const float* wp = wrow + nidx * 9;
#pragma unroll
                for (int k = 0; k < 9; k++) wnxt[k] = wp[k];
            }
#pragma unroll
            for (int r = 0; r < 7; r++) {
                double drow[7];
#pragma unroll
                for (int j = 0; j < 7; j++)
                    drow[j] = ind[cur][c * 144 + (base_ly + r) * 12 + base_lx + j];
#pragma unroll
                for (int dy = 0; dy < 3; dy++) {
                    const int iy = r - dy;
                    if (iy >= 0 && iy < 5) {
#pragma unroll
                        for (int dx = 0; dx < 3; dx++) {
                            const double wdv = wd[dy * 3 + dx];
#pragma unroll
                            for (int ix = 0; ix < 5; ix++)
                                acc[iy][ix] = fma(wdv, drow[ix + dx], acc[iy][ix]);
                        }
                    }
                }
            }
        }
        __syncthreads();
    }

    double* po = parts + (size_t)s * PART_ELEMS + (size_t)(n * COUT + oc0 + oc_l) * SPAT;
#pragma unroll
    for (int iy = 0; iy < 5; iy++)
#pragma unroll
        for (int ix = 0; ix < 5; ix++)
            po[(y0 + base_ly + iy) * FW + (x0 + base_lx + ix)] = acc[iy][ix];
}

// ---------------------------------------------------------------- K2: fused combine + 1x1 heads + decode (fp64)
// R14: 50-position blocks (grid 50x8) -> 400B staging bursts (2x coalescing),
// LDS 73KB. Same fp64 math and summation order as R11-R13.
__global__ __launch_bounds__(256) void k_heads_fused(const double* __restrict__ parts,
                                                     int S,
                                                     const float* __restrict__ conv_b,
                                                     const float* __restrict__ cls_w,
                                                     const float* __restrict__ cls_b,
                                                     const float* __restrict__ bbox_w,
                                                     const float* __restrict__ bbox_b,
                                                     double* __restrict__ boxesd,
                                                     double* __restrict__ scored)
{
    __shared__ float feat[50 * 257];   // [p][c] pitch 257  (51.4 KB)
    __shared__ double outb[54 * 50];   // [outch][p]        (21.6 KB)
    const int blk = blockIdx.x, n = blockIdx.y;
    const int pos0 = blk * 50;
    const int t = threadIdx.x;

    for (int idx = t; idx < 12800; idx += 256) {
        int c = idx / 50, p = idx - c * 50;
        size_t base = (size_t)(n * COUT + c) * SPAT + pos0 + p;
        double a = parts[base];
        for (int sp = 1; sp < S; sp++) a += parts[(size_t)sp * PART_ELEMS + base];
        a += (double)conv_b[c];
        feat[p * 257 + c] = (float)a;
    }
    __syncthreads();

    for (int u = t; u < 2700; u += 256) {
        const int oc = u % 54, p = u / 54;
        const float* wp = (oc < 18) ? (cls_w + oc * COUT) : (bbox_w + (oc - 18) * COUT);
        double s = (double)((oc < 18) ? cls_b[oc] : bbox_b[oc - 18]);
        const float* fp = &feat[p * 257];
#pragma unroll 8
        for (int c = 0; c < COUT; c++) s = fma((double)wp[c], (double)fp[c], s);
        outb[oc * 50 + p] = s;
    }
    __syncthreads();

    // decode + clip: 50 pos x 9 anchors = 450
    for (int u = t; u < 450; u += 256) {
        const int p = u / 9, k = u - p * 9;
        const int pos = pos0 + p;
        const int y = pos / 50, x = pos - y * 50;
        const int ri = k / 3, si = k - ri * 3;
        const double ratio = (ri == 0) ? 0.5 : ((ri == 1) ? 1.0 : 2.0);
        const double size = (si == 0) ? 128.0 : ((si == 1) ? 256.0 : 512.0);
        const double hr = sqrt(ratio), wr = 1.0 / hr;
        const double wsz = wr * size, hsz = hr * size;
        const double bx0 = rint(-wsz * 0.5), by0 = rint(-hsz * 0.5);
        const double bx1 = rint(wsz * 0.5), by1 = rint(hsz * 0.5);
        const double sxf = (double)(x * 16), syf = (double)(y * 16);
        const double a0 = sxf + bx0, a1 = syf + by0, a2 = sxf + bx1, a3 = syf + by1;
        const double aw = a2 - a0, ah = a3 - a1;
        const double cx = a0 + 0.5 * aw, cy = a1 + 0.5 * ah;
        const double d0 = outb[(18 + k * 4 + 0) * 50 + p];
        const double d1 = outb[(18 + k * 4 + 1) * 50 + p];
        const double d2 = outb[(18 + k * 4 + 2) * 50 + p];
        const double d3 = outb[(18 + k * 4 + 3) * 50 + p];
        const double ncx = d0 * aw + cx, ncy = d1 * ah + cy;
        const double nw = exp(d2) * aw, nh = exp(d3) * ah;
        double x1 = ncx - 0.5 * nw, y1 = ncy - 0.5 * nh;
        double x2 = ncx + 0.5 * nw, y2 = ncy + 0.5 * nh;
        x1 = fmin(fmax(x1, 0.0), 800.0);
        y1 = fmin(fmax(y1, 0.0), 800.0);
        x2 = fmin(fmax(x2, 0.0), 800.0);
        y2 = fmin(fmax(y2, 0.0), 800.0);
        double* bp = boxesd + ((size_t)n * NANCH + pos * 9 + k) * 4;
        bp[0] = x1; bp[1] = y1; bp[2] = x2; bp[3] = y2;
    }
    // scores: odd positions only; 18 ch x 50 pos = 900
    for (int u = t; u < 900; u += 256) {
        const int ch = u / 50, p = u - ch * 50;
        const int pos = pos0 + p;
        if (pos & 1) {
            const int a = ch * 1250 + ((pos - 1) >> 1);
            const double v = outb[ch * 50 + p];
            scored[(size_t)n * NANCH + a] = 1.0 / (1.0 + exp(-v));
        }
    }
}

// ---------------------------------------------------------------- K3a: parallel key build
__global__ __launch_bounds__(256) void k_keys(const double* __restrict__ boxesd,
                                              const double* __restrict__ scored,
                                              uint64_t* __restrict__ keys)
{
    const int n = blockIdx.y;
    const int a = blockIdx.x * 256 + threadIdx.x;
    if (a < NANCH) {
        const double* bp = boxesd + ((size_t)n * NANCH + a) * 4;
        double x1 = bp[0], y1 = bp[1], x2 = bp[2], y2 = bp[3];
        double s0 = scored[(size_t)n * NANCH + a];
        bool valid = (x2 - x1 >= 16.0) && (y2 - y1 >= 16.0) && (s0 > 0.05);
        double s = valid ? s0 : -1.0;
        uint64_t b = (uint64_t)__double_as_longlong(s);
        uint64_t su = (b >> 63) ? ~b : (b | 0x8000000000000000ull);
        keys[(size_t)n * NANCH + a] = su;
    }
}

// ---------------------------------------------------------------- K3b: per-image exact top-1000 (R13 proven)
__global__ __launch_bounds__(1024) void k_select(const double* __restrict__ boxesd,
                                                 const uint64_t* __restrict__ keys,
                                                 double* __restrict__ tbd,
                                                 float* __restrict__ topv)
{
    __shared__ unsigned hist[256];
    __shared__ uint64_t candk[2048];
    __shared__ uint32_t candi[2048];
    __shared__ __align__(16) uint64_t sel2[2048];
    __shared__ __align__(16) uint64_t out2[2048];
    __shared__ uint64_t sh_prefix, sh_mask;
    __shared__ unsigned sh_rem, sh_binc, sh_cnt, sh_cntA, sh_cntB;

    const int n = blockIdx.x, t = threadIdx.x;
    const uint64_t* ky = keys + (size_t)n * NANCH;

    if (t == 0) { sh_prefix = 0; sh_mask = 0; sh_rem = KTOP; }
    __syncthreads();

    auto radix_pass = [&](int shift, bool useCand) {
        if (t < 256) hist[t] = 0;
        __syncthreads();
        const uint64_t pre = sh_prefix, msk = sh_mask;
        if (!useCand) {
            for (int a = t; a < NANCH; a += 1024) {
                uint64_t k = ky[a];
                if ((k & msk) == pre)
                    atomicAdd(&hist[(unsigned)((k >> shift) & 255)], 1u);
            }
        } else {
            const unsigned nc = sh_cnt;
            for (unsigned j = t; j < nc; j += 1024) {
                uint64_t k = candk[j];
                if ((k & msk) == pre)
                    atomicAdd(&hist[(unsigned)((k >> shift) & 255)], 1u);
            }
        }
        __syncthreads();
        if (t < 64) {
            unsigned h0 = hist[4 * t], h1 = hist[4 * t + 1];
            unsigned h2 = hist[4 * t + 2], h3 = hist[4 * t + 3];
            unsigned local = h0 + h1 + h2 + h3;
            unsigned suf = local;
#pragma unroll
            for (int off = 1; off < 64; off <<= 1) {
                unsigned x = __shfl_down(suf, off);
                if (t + off < 64) suf += x;
            }
            unsigned exclc = suf - local;
            unsigned inc3 = exclc + h3;
            unsigned inc2 = inc3 + h2;
            unsigned inc1 = inc2 + h1;
            unsigned inc0 = inc1 + h0;
            const unsigned rem = sh_rem;
            int cand = -1; unsigned candExcl = 0;
            if      (inc3 >= rem) { cand = 4 * t + 3; candExcl = exclc; }
            else if (inc2 >= rem) { cand = 4 * t + 2; candExcl = inc3; }
            else if (inc1 >= rem) { cand = 4 * t + 1; candExcl = inc2; }
            else if (inc0 >= rem) { cand = 4 * t + 0; candExcl = inc1; }
#pragma unroll
            for (int off = 32; off > 0; off >>= 1) {
                int c2 = __shfl_down(cand, off);
                unsigned p2 = __shfl_down(candExcl, off);
                if (c2 > cand) { cand = c2; candExcl = p2; }
            }
            if (t == 0) {
                sh_prefix = pre | ((uint64_t)(unsigned)cand << shift);
                sh_mask = msk | (255ull << shift);
                sh_rem = rem - candExcl;
                sh_binc = hist[cand];
            }
        }
        __syncthreads();
    };

    radix_pass(56, false);
    radix_pass(48, false);

    if (t == 0) sh_cnt = 0;
    __syncthreads();
    const bool compacted = (sh_binc <= 2048u);
    if (compacted) {
        const uint64_t pre = sh_prefix, msk = sh_mask;
        for (int a = t; a < NANCH; a += 1024) {
            uint64_t k = ky[a];
            if ((k & msk) == pre) {
                unsigned p = atomicAdd(&sh_cnt, 1u);
                candk[p] = k; candi[p] = (uint32_t)a;
            }
        }
    }
    __syncthreads();

    for (int pass = 2; pass < 8; pass++)
        radix_pass(56 - 8 * pass, compacted);

    const uint64_t T = sh_prefix;

    sel2[2 * t] = 0; sel2[2 * t + 1] = 0;
    if (t == 0) { sh_cntA = 0; sh_cntB = 0; }
    __syncthreads();
    for (int a = t; a < NANCH; a += 1024) {
        uint64_t k = ky[a];
        if (k > T) {
            unsigned p = atomicAdd(&sh_cntA, 1u);
            sel2[2 * p] = k; sel2[2 * p + 1] = (uint64_t)(~(uint32_t)a);
        }
    }
    __syncthreads();
    const unsigned m = sh_cntA;
    if (compacted) {
        const unsigned nc = sh_cnt;
        for (unsigned j = t; j < nc; j += 1024) {
            if (candk[j] == T) {
                unsigned q = atomicAdd(&sh_cntB, 1u);
                unsigned slot = m + q;
                if (slot < KTOP) { sel2[2 * slot] = T; sel2[2 * slot + 1] = (uint64_t)(~candi[j]); }
            }
        }
    } else {
        for (int a = t; a < NANCH; a += 1024) {
            if (ky[a] == T) {
                unsigned q = atomicAdd(&sh_cntB, 1u);
                unsigned slot = m + q;
                if (slot < KTOP) { sel2[2 * slot] = T; sel2[2 * slot + 1] = (uint64_t)(~(uint32_t)a); }
            }
        }
    }
    __syncthreads();
    {
        const uint64_t myk = sel2[2 * t], myn = sel2[2 * t + 1];
        int rank = 0;
        const ulonglong2* sp = (const ulonglong2*)sel2;
#pragma unroll 8
        for (int j = 0; j < 1024; j++) {
            ulonglong2 v = sp[j];
            rank += (v.x > myk) || (v.x == myk && v.y > myn);
        }
        if (rank < KTOP) { out2[2 * rank] = myk; out2[2 * rank + 1] = myn; }
    }
    __syncthreads();

    if (t < KTOP) {
        uint64_t k = out2[2 * t];
        uint32_t idx = ~(uint32_t)out2[2 * t + 1];
        uint64_t b = (k >> 63) ? (k ^ 0x8000000000000000ull) : ~k;
        double s = __longlong_as_double((long long)b);
        double bx0 = 0.0, bx1 = 0.0, bx2 = 0.0, bx3 = 0.0;
        float sv = (float)s;
        if (idx < NANCH) {
            const double* bp = boxesd + ((size_t)n * NANCH + idx) * 4;
            bx0 = bp[0]; bx1 = bp[1]; bx2 = bp[2]; bx3 = bp[3];
        } else {
            sv = -1.0f;
        }
        double* tp = tbd + ((size_t)n * KTOP + t) * 4;
        tp[0] = bx0; tp[1] = bx1; tp[2] = bx2; tp[3] = bx3;
        topv[n * KTOP + t] = sv;
    }
}

// ---------------------------------------------------------------- K4a: suppression bit-matrix (fp64 IoU)
__global__ __launch_bounds__(256) void k_supmat(const double* __restrict__ tbd,
                                                uint64_t* __restrict__ sup)
{
    __shared__ double sb[4000];
    const int tile = blockIdx.x, n = blockIdx.y;
    const int t = threadIdx.x;
    for (int i = t; i < 4000; i += 256) sb[i] = tbd[(size_t)n * KTOP * 4 + i];
    __syncthreads();
    const int r0 = tile * 64;
    for (int u = t; u < 1024; u += 256) {
        const int il = u >> 4, wq = u & 15;
        const int i = r0 + il;
        if (i >= 1000) continue;
        const double bix = sb[i * 4], biy = sb[i * 4 + 1], biz = sb[i * 4 + 2], biw = sb[i * 4 + 3];
        const double ai = (biz - bix) * (biw - biy);
        uint64_t bits = 0;
        const int jbase = wq * 64;
        for (int jj = 0; jj < 64; jj++) {
            const int j = jbase + jj;
            if (j < 1000 && j > i) {
                const double bjx = sb[j * 4], bjy = sb[j * 4 + 1], bjz = sb[j * 4 + 2], bjw = sb[j * 4 + 3];
                const double aj = (bjz - bjx) * (bjw - bjy);
                const double ltx = fmax(bix, bjx), lty = fmax(biy, bjy);
                const double rbx = fmin(biz, bjz), rby = fmin(biw, bjw);
                const double ww = fmax(rbx - ltx, 0.0), hh = fmax(rby - lty, 0.0);
                const double inter = ww * hh;
                const double iou = inter / (ai + aj - inter + 1e-8);
                if (iou > 0.7) bits |= (1ull << jj);
            }
        }
        sup[((size_t)n * KTOP + i) * 16 + wq] = bits;
    }
}

// ---------------------------------------------------------------- K4b+K5 fused: NMS scan (wave 0) + compaction (block)
__global__ __launch_bounds__(1024) void k_nms_final(const uint64_t* __restrict__ sup,
                                                    const float* __restrict__ topv,
                                                    const double* __restrict__ tbd,
                                                    float* __restrict__ out)
{
    __shared__ uint64_t kw[16];
    __shared__ int sc[1024];
    __shared__ int sh_total;
    const int n = blockIdx.x, t = threadIdx.x;

    // ---- wave 0: sequential bitmask NMS scan (identical to proven k_nms)
    if (t < 64) {
        const int lane = t;
        const uint64_t* rows = sup + (size_t)n * KTOP * 16;
        uint64_t keep;
        if (lane < 15) keep = ~0ull;
        else if (lane == 15) keep = (1ull << 40) - 1;
        else keep = 0;

        uint64_t A[8], B[8];
        auto LOADG = [&](uint64_t* dst, int g) {
#pragma unroll
            for (int k = 0; k < 8; k++) {
                int i = g * 8 + k;
                dst[k] = (lane < 16) ? rows[(size_t)i * 16 + lane] : 0ull;
            }
        };
        auto PROCG = [&](const uint64_t* src, int g) {
#pragma unroll
            for (int k = 0; k < 8; k++) {
                int i = g * 8 + k;
                uint64_t w = __shfl(keep, i >> 6);
                bool alive = (w >> (i & 63)) & 1ull;
                keep &= alive ? ~src[k] : ~0ull;
            }
        };
        LOADG(A, 0);
        for (int g = 0; g < 125; g += 2) {
            if (g + 1 < 125) LOADG(B, g + 1);
            PROCG(A, g);
            if (g + 2 < 125) LOADG(A, g + 2);
            if (g + 1 < 125) PROCG(B, g + 1);
        }
        if (lane < 16) kw[lane] = keep;
    }
    __syncthreads();

    // ---- whole block: stable compaction (identical to proven k_final)
    int val = 0;
    bool kept = false;
    if (t < 1000) {
        bool bit = (kw[t >> 6] >> (t & 63)) & 1ull;
        float v = topv[n * KTOP + t];
        kept = bit && (v > 0.0f);
        val = kept ? 1 : 0;
    }
    sc[t] = val;
    __syncthreads();
    for (int off = 1; off < 1024; off <<= 1) {
        int x = (t >= off) ? sc[t - off] : 0;
        __syncthreads();
        sc[t] += x;
        __syncthreads();
    }
    if (t == 1023) sh_total = sc[1023];
    __syncthreads();
    const int total = sh_total;
    if (t < 1000) {
        if (kept) {
            int r = sc[t] - 1;
            const double* bp = tbd + ((size_t)n * KTOP + t) * 4;
            float* o = out + ((size_t)n * KTOP + r) * 5;
            o[0] = (float)bp[0]; o[1] = (float)bp[1];
            o[2] = (float)bp[2]; o[3] = (float)bp[3];
            o[4] = (float)n;
        }
        if (t >= total) {
            float* o = out + ((size_t)n * KTOP + t) * 5;
            o[0] = 0.0f; o[1] = 0.0f; o[2] = 0.0f; o[3] = 0.0f; o[4] = (float)n;
        }
    }
}

// ---------------------------------------------------------------- legacy fallback conv + heads (R8 proven)
__global__ __launch_bounds__(128) void k_conv3_full(const float* __restrict__ in,
                                                    const float* __restrict__ w,
                                                    const float* __restrict__ bias,
                                                    float* __restrict__ out)
{
    __shared__ double ind[2][672];
    const int tile = blockIdx.x, ocg = blockIdx.y, n = blockIdx.z;
    const int ty = tile / 5, tx = tile % 5;
    const int y0 = ty * 5, x0 = tx * 10;
    const int t = threadIdx.x;
    const int oc_l = t & 63;
    const int g = t >> 6;
    const int base_lx = g * 5;
    const int oc0 = ocg * 64;

    int soff[6];
#pragma unroll
    for (int k = 0; k < 6; k++) {
        int idx = t + k * 128;
        soff[k] = -1;
        if (idx < 672) {
            int c = idx / 84, rem = idx - c * 84;
            int iy = rem / 12, ix = rem - iy * 12;
            int y = y0 - 1 + iy, x = x0 - 1 + ix;
            if ((unsigned)y < 50u && (unsigned)x < 50u)
                soff[k] = (n * CIN + c) * SPAT + y * FW + x;
        }
    }
    const float* wrow = w + (size_t)(oc0 + oc_l) * (CIN * 9);
    double acc[5][5];
#pragma unroll
    for (int i = 0; i < 5; i++)
#pragma unroll
        for (int j = 0; j < 5; j++) acc[i][j] = 0.0;
    float rin[6];
#pragma unroll
    for (int k = 0; k < 6; k++) rin[k] = (soff[k] >= 0) ? in[soff[k]] : 0.0f;
    float wnxt[9];
#pragma unroll
    for (int k = 0; k < 9; k++) wnxt[k] = wrow[k];

    for (int cc = 0; cc < 64; ++cc) {
        const int cur = cc & 1;
#pragma unroll
        for (int k = 0; k < 6; k++) {
            int idx = t + k * 128;
            if (idx < 672) ind[cur][idx] = (double)rin[k];
        }
        __syncthreads();
        if (cc < 63) {
            const int coff = (cc + 1) * (8 * SPAT);
#pragma unroll
            for (int k = 0; k < 6; k++)
                rin[k] = (soff[k] >= 0) ? in[soff[k] + coff] : 0.0f;
        }
#pragma unroll 1
        for (int c = 0; c < 8; c++) {
            double wd[9];
#pragma unroll
            for (int k = 0; k < 9; k++) wd[k] = (double)wnxt[k];
            const int nidx = cc * 8 + c + 1;
            if (nidx < 512) {
                const float* wp = wrow + nidx * 9;
#pragma unroll
                for (int k = 0; k < 9; k++) wnxt[k] = wp[k];
            }
#pragma unroll
            for (int r = 0; r < 7; r++) {
                double drow[7];
#pragma unroll
                for (int j = 0; j < 7; j++)
                    drow[j] = ind[cur][c * 84 + r * 12 + base_lx + j];
#pragma unroll
                for (int dy = 0; dy < 3; dy++) {
                    const int iy = r - dy;
                    if (iy >= 0 && iy < 5) {
#pragma unroll
                        for (int dx = 0; dx < 3; dx++) {
                            const double wdv = wd[dy * 3 + dx];
#pragma unroll
                            for (int ix = 0; ix < 5; ix++)
                                acc[iy][ix] = fma(wdv, drow[ix + dx], acc[iy][ix]);
                        }
                    }
                }
            }
        }
        __syncthreads();
    }
    const double b = (double)bias[oc0 + oc_l];
#pragma unroll
    for (int iy = 0; iy < 5; iy++)
#pragma unroll
        for (int ix = 0; ix < 5; ix++) {
            int y = y0 + iy, x = x0 + base_lx + ix;
            out[(n * COUT + oc0 + oc_l) * SPAT + y * FW + x] = (float)(acc[iy][ix] + b);
        }
}

__global__ __launch_bounds__(256) void k_heads_legacy(const float* __restrict__ conv1,
                                                      const float* __restrict__ cls_w,
                                                      const float* __restrict__ cls_b,
                                                      const float* __restrict__ bbox_w,
                                                      const float* __restrict__ bbox_b,
                                                      double* __restrict__ boxesd,
                                                      double* __restrict__ scored)
{
    __shared__ float feat[25 * 257];
    __shared__ double outb[54 * 25];
    const int blk = blockIdx.x, n = blockIdx.y;
    const int pos0 = blk * 25;
    const int t = threadIdx.x;

    for (int idx = t; idx < 6400; idx += 256) {
        int c = idx / 25, p = idx - c * 25;
        feat[p * 257 + c] = conv1[(n * COUT + c) * SPAT + pos0 + p];
    }
    __syncthreads();
    for (int u = t; u < 1350; u += 256) {
        const int oc = u % 54, p = u / 54;
        const float* wp = (oc < 18) ? (cls_w + oc * COUT) : (bbox_w + (oc - 18) * COUT);
        double s = (double)((oc < 18) ? cls_b[oc] : bbox_b[oc - 18]);
        const float* fp = &feat[p * 257];
#pragma unroll 8
        for (int c = 0; c < COUT; c++) s = fma((double)wp[c], (double)fp[c], s);
        outb[oc * 25 + p] = s;
    }
    __syncthreads();
    if (t < 225) {
        const int p = t / 9, k = t - p * 9;
        const int pos = pos0 + p;
        const int y = pos / 50, x = pos - y * 50;
        const int ri = k / 3, si = k - ri * 3;
        const double ratio = (ri == 0) ? 0.5 : ((ri == 1) ? 1.0 : 2.0);
        const double size = (si == 0) ? 128.0 : ((si == 1) ? 256.0 : 512.0);
        const double hr = sqrt(ratio), wr = 1.0 / hr;
        const double wsz = wr * size, hsz = hr * size;
        const double bx0 = rint(-wsz * 0.5), by0 = rint(-hsz * 0.5);
        const double bx1 = rint(wsz * 0.5), by1 = rint(hsz * 0.5);
        const double sxf = (double)(x * 16), syf = (double)(y * 16);
        const double a0 = sxf + bx0, a1 = syf + by0, a2 = sxf + bx1, a3 = syf + by1;
        const double aw = a2 - a0, ah = a3 - a1;
        const double cx = a0 + 0.5 * aw, cy = a1 + 0.5 * ah;
        const double d0 = outb[(18 + k * 4 + 0) * 25 + p];
        const double d1 = outb[(18 + k * 4 + 1) * 25 + p];
        const double d2 = outb[(18 + k * 4 + 2) * 25 + p];
        const double d3 = outb[(18 + k * 4 + 3) * 25 + p];
        const double ncx = d0 * aw + cx, ncy = d1 * ah + cy;
        const double nw = exp(d2) * aw, nh = exp(d3) * ah;
        double x1 = ncx - 0.5 * nw, y1 = ncy - 0.5 * nh;
        double x2 = ncx + 0.5 * nw, y2 = ncy + 0.5 * nh;
        x1 = fmin(fmax(x1, 0.0), 800.0);
        y1 = fmin(fmax(y1, 0.0), 800.0);
        x2 = fmin(fmax(x2, 0.0), 800.0);
        y2 = fmin(fmax(y2, 0.0), 800.0);
        double* bp = boxesd + ((size_t)n * NANCH + pos * 9 + k) * 4;
        bp[0] = x1; bp[1] = y1; bp[2] = x2; bp[3] = y2;
    }
    for (int u = t; u < 450; u += 256) {
        const int ch = u / 25, p = u - ch * 25;
        const int pos = pos0 + p;
        if (pos & 1) {
            const int a = ch * 1250 + ((pos - 1) >> 1);
            const double v = outb[ch * 25 + p];
            scored[(size_t)n * NANCH + a] = 1.0 / (1.0 + exp(-v));
        }
    }
}

// ---------------------------------------------------------------- launch
extern "C" void kernel_launch(void* const* d_in, const int* in_sizes, int n_in,
                              void* d_out, int out_size, void* d_ws, size_t ws_size,
                              hipStream_t stream)
{
    (void)in_sizes; (void)n_in; (void)out_size;
    const float* feat   = (const float*)d_in[1];
    const float* conv_w = (const float*)d_in[2];
    const float* conv_b = (const float*)d_in[3];
    const float* cls_w  = (const float*)d_in[4];
    const float* cls_b  = (const float*)d_in[5];
    const float* bbox_w = (const float*)d_in[6];
    const float* bbox_b = (const float*)d_in[7];
    float* out = (float*)d_out;
    char* ws = (char*)d_ws;

    const size_t PB   = 40960000ull;
    const size_t REST = 5760000 + 1440000 + 1440000 + 256000 + 32000 + 1024000 + 1024;

    int S = 0;
    if      (ws_size >= 4 * PB + REST) S = 4;
    else if (ws_size >= 2 * PB + REST) S = 2;
    else if (ws_size >= 1 * PB + REST) S = 1;

    if (S > 0) {
        double*   parts  = (double*)ws;
        char*     p      = ws + (size_t)S * PB;
        double*   boxesd = (double*)(p);               p += 5760000;
        double*   scored = (double*)(p);               p += 1440000;
        uint64_t* keys   = (uint64_t*)(p);             p += 1440000;
        double*   tbd    = (double*)(p);               p += 256000;
        float*    topv   = (float*)(p);                p += 32000;
        uint64_t* sup    = (uint64_t*)(p);

        k_conv3_part <<<dim3(25, 4, 8 * S), 256, 0, stream>>>(feat, conv_w, parts, S);
        k_heads_fused<<<dim3(50, 8), 256, 0, stream>>>(parts, S, conv_b, cls_w, cls_b,
                                                       bbox_w, bbox_b, boxesd, scored);
        k_keys     <<<dim3(88, 8), 256, 0, stream>>>(boxesd, scored, keys);
        k_select   <<<8, 1024, 0, stream>>>(boxesd, keys, tbd, topv);
        k_supmat   <<<dim3(16, 8), 256, 0, stream>>>(tbd, sup);
        k_nms_final<<<8, 1024, 0, stream>>>(sup, topv, tbd, out);
    } else {
        float*    conv1  = (float*)(ws);
        double*   boxesd = (double*)(ws + 20480000);
        double*   scored = (double*)(ws + 26240000);
        uint64_t* keys   = (uint64_t*)(ws + 27680000);
        double*   tbd    = (double*)(ws + 29120000);
        float*    topv   = (float*)(ws + 29376000);
        uint64_t* sup    = (uint64_t*)(ws + 29408000);

        k_conv3_full  <<<dim3(50, 4, 8), 128, 0, stream>>>(feat, conv_w, conv_b, conv1);
        k_heads_legacy<<<dim3(100, 8), 256, 0, stream>>>(conv1, cls_w, cls_b, bbox_w, bbox_b, boxesd, scored);
        k_keys     <<<dim3(88, 8), 256, 0, stream>>>(boxesd, scored, keys);
        k_select   <<<8, 1024, 0, stream>>>(boxesd, keys, tbd, topv);
        k_supmat   <<<dim3(16, 8), 256, 0, stream>>>(tbd, sup);
        k_nms_final<<<8, 1024, 0, stream>>>(sup, topv, tbd, out);
    }
}

// Round 15
// 1492.529 us; speedup vs baseline: 1.0172x; 1.0172x over previous
//
#include <hip/hip_runtime.h>
#include <cstdint>

#define N_IMG 8
#define CIN 512
#define COUT 256
#define FH 50
#define FW 50
#define SPAT 2500
#define NANCH 22500
#define KTOP 1000
#define PART_ELEMS 5120000   // 8*256*2500

// ---------------------------------------------------------------- K1: 3x3 SAME conv, fp64 accumulate, cin-split S parts
// R15: pair-staged LDS (2 cc-chunks per barrier) + redundant trailing barrier
// removed -> 8 barriers/block (was 32). block 256 = 64 oc x 4 groups(5x5);
// tile 10x10; grid (25 tiles, 4 ocg, 8*S). Per-element accumulation order
// (cc asc, c asc, tap asc) identical to R3..R14 -> bit-identical partials.
__global__ __launch_bounds__(256) void k_conv3_part(const float* __restrict__ in,
                                                    const float* __restrict__ w,
                                                    double* __restrict__ parts,
                                                    int S)
{
    __shared__ double ind[2][2304];   // [buf][chan*144 + iy*12 + ix], chan=half*8+c  (36,864 B)

    const int tile = blockIdx.x, ocg = blockIdx.y;
    const int n = blockIdx.z / S, s = blockIdx.z - n * S;
    const int ccp = 64 / S;            // cc-chunks per block (16/32/64 -> even)
    const int npair = ccp >> 1;
    const int pp0 = (s * ccp) >> 1;    // first pair index
    const int cc1 = s * ccp + ccp;     // end cc (for weight prefetch guard)
    const int ty = tile / 5, tx = tile % 5;
    const int y0 = ty * 10, x0 = tx * 10;
    const int t = threadIdx.x;
    const int oc_l = t & 63;
    const int g = t >> 6;                         // group 0..3
    const int base_ly = (g >> 1) * 5, base_lx = (g & 1) * 5;
    const int oc0 = ocg * 64;

    // staging slots: idx = t + 256k, k<9, idx<2304 ; 16 channels x 12x12 halo
    int soff[9];
#pragma unroll
    for (int k = 0; k < 9; k++) {
        int idx = t + k * 256;
        soff[k] = -1;
        if (idx < 2304) {
            int chan = idx / 144, rem = idx - chan * 144;
            int iy = rem / 12, ix = rem - iy * 12;
            int y = y0 - 1 + iy, x = x0 - 1 + ix;
            if ((unsigned)y < 50u && (unsigned)x < 50u)
                soff[k] = (n * CIN + chan) * SPAT + y * FW + x;
        }
    }

    const float* wrow = w + (size_t)(oc0 + oc_l) * (CIN * 9);

    double acc[5][5];
#pragma unroll
    for (int i = 0; i < 5; i++)
#pragma unroll
        for (int j = 0; j < 5; j++) acc[i][j] = 0.0;

    // prologue: input(pair pp0) -> regs ; weights(cc0, c=0) -> regs
    float rin[9];
    {
        const int poff0 = pp0 * (16 * SPAT);
#pragma unroll
        for (int k = 0; k < 9; k++) rin[k] = (soff[k] >= 0) ? in[soff[k] + poff0] : 0.0f;
    }
    float wnxt[9];
    {
        const float* wp0 = wrow + (s * ccp) * 72;
#pragma unroll
        for (int k = 0; k < 9; k++) wnxt[k] = wp0[k];
    }

    for (int pp = pp0; pp < pp0 + npair; ++pp) {
        const int cur = pp & 1;
        // write staged pair (fp64) into current buffer
#pragma unroll
        for (int k = 0; k < 9; k++) {
            int idx = t + k * 256;
            if (idx < 2304) ind[cur][idx] = (double)rin[k];
        }
        __syncthreads();   // ONE barrier per pair; trailing barrier provably redundant

        // prefetch next pair's input (hides under 3600 FMAs)
        if (pp + 1 < pp0 + npair) {
            const int poff = (pp + 1) * (16 * SPAT);
#pragma unroll
            for (int k = 0; k < 9; k++)
                rin[k] = (soff[k] >= 0) ? in[soff[k] + poff] : 0.0f;
        }

#pragma unroll 1
        for (int half = 0; half < 2; ++half) {
            const int cc = 2 * pp + half;
#pragma unroll 1
            for (int c = 0; c < 8; c++) {
                double wd[9];
#pragma unroll
                for (int k = 0; k < 9; k++) wd[k] = (double)wnxt[k];
                const int nidx = cc * 8 + c + 1;
                if (nidx < cc1 * 8) {
                    const float* wp = wrow + nidx * 9;
#pragma unroll
                    for (int k = 0; k < 9; k++) wnxt[k] = wp[k];
                }
                const int cbase = (half * 8 + c) * 144;
#pragma unroll
                for (int r = 0; r < 7; r++) {
                    double drow[7];
#pragma unroll
                    for (int j = 0; j < 7; j++)
                        drow[j] = ind[cur][cbase + (base_ly + r) * 12 + base_lx + j];
#pragma unroll
                    for (int dy = 0; dy < 3; dy++) {
                        const int iy = r - dy;
                        if (iy >= 0 && iy < 5) {
#pragma unroll
                            for (int dx = 0; dx < 3; dx++) {
                                const double wdv = wd[dy * 3 + dx];
#pragma unroll
                                for (int ix = 0; ix < 5; ix++)
                                    acc[iy][ix] = fma(wdv, drow[ix + dx], acc[iy][ix]);
                            }
                        }
                    }
                }
            }
        }
        // no trailing barrier: next pair writes ind[cur^1]; the pair after next
        // writes ind[cur] only after the NEXT top barrier, by which time all
        // reads of ind[cur] (program-order before that barrier) are complete.
    }

    double* po = parts + (size_t)s * PART_ELEMS + (size_t)(n * COUT + oc0 + oc_l) * SPAT;
#pragma unroll
    for (int iy = 0; iy < 5; iy++)
#pragma unroll
        for (int ix = 0; ix < 5; ix++)
            po[(y0 + base_ly + iy) * FW + (x0 + base_lx + ix)] = acc[iy][ix];
}

// ---------------------------------------------------------------- K2: fused combine + 1x1 heads + decode (fp64) [R13 proven]
__global__ __launch_bounds__(256) void k_heads_fused(const double* __restrict__ parts,
                                                     int S,
                                                     const float* __restrict__ conv_b,
                                                     const float* __restrict__ cls_w,
                                                     const float* __restrict__ cls_b,
                                                     const float* __restrict__ bbox_w,
                                                     const float* __restrict__ bbox_b,
                                                     double* __restrict__ boxesd,
                                                     double* __restrict__ scored)
{
    __shared__ float feat[25 * 257];
    __shared__ double outb[54 * 25];
    const int blk = blockIdx.x, n = blockIdx.y;
    const int pos0 = blk * 25;
    const int t = threadIdx.x;

    for (int idx = t; idx < 6400; idx += 256) {
        int c = idx / 25, p = idx - c * 25;
        size_t base = (size_t)(n * COUT + c) * SPAT + pos0 + p;
        double a = parts[base];
        for (int sp = 1; sp < S; sp++) a += parts[(size_t)sp * PART_ELEMS + base];
        a += (double)conv_b[c];
        feat[p * 257 + c] = (float)a;
    }
    __syncthreads();

    for (int u = t; u < 1350; u += 256) {
        const int oc = u % 54, p = u / 54;
        const float* wp = (oc < 18) ? (cls_w + oc * COUT) : (bbox_w + (oc - 18) * COUT);
        double s = (double)((oc < 18) ? cls_b[oc] : bbox_b[oc - 18]);
        const float* fp = &feat[p * 257];
#pragma unroll 8
        for (int c = 0; c < COUT; c++) s = fma((double)wp[c], (double)fp[c], s);
        outb[oc * 25 + p] = s;
    }
    __syncthreads();

    if (t < 225) {
        const int p = t / 9, k = t - p * 9;
        const int pos = pos0 + p;
        const int y = pos / 50, x = pos - y * 50;
        const int ri = k / 3, si = k - ri * 3;
        const double ratio = (ri == 0) ? 0.5 : ((ri == 1) ? 1.0 : 2.0);
        const double size = (si == 0) ? 128.0 : ((si == 1) ? 256.0 : 512.0);
        const double hr = sqrt(ratio), wr = 1.0 / hr;
        const double wsz = wr * size, hsz = hr * size;
        const double bx0 = rint(-wsz * 0.5), by0 = rint(-hsz * 0.5);
        const double bx1 = rint(wsz * 0.5), by1 = rint(hsz * 0.5);
        const double sxf = (double)(x * 16), syf = (double)(y * 16);
        const double a0 = sxf + bx0, a1 = syf + by0, a2 = sxf + bx1, a3 = syf + by1;
        const double aw = a2 - a0, ah = a3 - a1;
        const double cx = a0 + 0.5 * aw, cy = a1 + 0.5 * ah;
        const double d0 = outb[(18 + k * 4 + 0) * 25 + p];
        const double d1 = outb[(18 + k * 4 + 1) * 25 + p];
        const double d2 = outb[(18 + k * 4 + 2) * 25 + p];
        const double d3 = outb[(18 + k * 4 + 3) * 25 + p];
        const double ncx = d0 * aw + cx, ncy = d1 * ah + cy;
        const double nw = exp(d2) * aw, nh = exp(d3) * ah;
        double x1 = ncx - 0.5 * nw, y1 = ncy - 0.5 * nh;
        double x2 = ncx + 0.5 * nw, y2 = ncy + 0.5 * nh;
        x1 = fmin(fmax(x1, 0.0), 800.0);
        y1 = fmin(fmax(y1, 0.0), 800.0);
        x2 = fmin(fmax(x2, 0.0), 800.0);
        y2 = fmin(fmax(y2, 0.0), 800.0);
        double* bp = boxesd + ((size_t)n * NANCH + pos * 9 + k) * 4;
        bp[0] = x1; bp[1] = y1; bp[2] = x2; bp[3] = y2;
    }
    for (int u = t; u < 450; u += 256) {
        const int ch = u / 25, p = u - ch * 25;
        const int pos = pos0 + p;
        if (pos & 1) {
            const int a = ch * 1250 + ((pos - 1) >> 1);
            const double v = outb[ch * 25 + p];
            scored[(size_t)n * NANCH + a] = 1.0 / (1.0 + exp(-v));
        }
    }
}

// ---------------------------------------------------------------- K3a: parallel key build [R13 proven]
__global__ __launch_bounds__(256) void k_keys(const double* __restrict__ boxesd,
                                              const double* __restrict__ scored,
                                              uint64_t* __restrict__ keys)
{
    const int n = blockIdx.y;
    const int a = blockIdx.x * 256 + threadIdx.x;
    if (a < NANCH) {
        const double* bp = boxesd + ((size_t)n * NANCH + a) * 4;
        double x1 = bp[0], y1 = bp[1], x2 = bp[2], y2 = bp[3];
        double s0 = scored[(size_t)n * NANCH + a];
        bool valid = (x2 - x1 >= 16.0) && (y2 - y1 >= 16.0) && (s0 > 0.05);
        double s = valid ? s0 : -1.0;
        uint64_t b = (uint64_t)__double_as_longlong(s);
        uint64_t su = (b >> 63) ? ~b : (b | 0x8000000000000000ull);
        keys[(size_t)n * NANCH + a] = su;
    }
}

// ---------------------------------------------------------------- K3b: per-image exact top-1000 [R13 proven]
__global__ __launch_bounds__(1024) void k_select(const double* __restrict__ boxesd,
                                                 const uint64_t* __restrict__ keys,
                                                 double* __restrict__ tbd,
                                                 float* __restrict__ topv)
{
    __shared__ unsigned hist[256];
    __shared__ uint64_t candk[2048];
    __shared__ uint32_t candi[2048];
    __shared__ __align__(16) uint64_t sel2[2048];
    __shared__ __align__(16) uint64_t out2[2048];
    __shared__ uint64_t sh_prefix, sh_mask;
    __shared__ unsigned sh_rem, sh_binc, sh_cnt, sh_cntA, sh_cntB;

    const int n = blockIdx.x, t = threadIdx.x;
    const uint64_t* ky = keys + (size_t)n * NANCH;

    if (t == 0) { sh_prefix = 0; sh_mask = 0; sh_rem = KTOP; }
    __syncthreads();

    auto radix_pass = [&](int shift, bool useCand) {
        if (t < 256) hist[t] = 0;
        __syncthreads();
        const uint64_t pre = sh_prefix, msk = sh_mask;
        if (!useCand) {
            for (int a = t; a < NANCH; a += 1024) {
                uint64_t k = ky[a];
                if ((k & msk) == pre)
                    atomicAdd(&hist[(unsigned)((k >> shift) & 255)], 1u);
            }
        } else {
            const unsigned nc = sh_cnt;
            for (unsigned j = t; j < nc; j += 1024) {
                uint64_t k = candk[j];
                if ((k & msk) == pre)
                    atomicAdd(&hist[(unsigned)((k >> shift) & 255)], 1u);
            }
        }
        __syncthreads();
        if (t < 64) {
            unsigned h0 = hist[4 * t], h1 = hist[4 * t + 1];
            unsigned h2 = hist[4 * t + 2], h3 = hist[4 * t + 3];
            unsigned local = h0 + h1 + h2 + h3;
            unsigned suf = local;
#pragma unroll
            for (int off = 1; off < 64; off <<= 1) {
                unsigned x = __shfl_down(suf, off);
                if (t + off < 64) suf += x;
            }
            unsigned exclc = suf - local;
            unsigned inc3 = exclc + h3;
            unsigned inc2 = inc3 + h2;
            unsigned inc1 = inc2 + h1;
            unsigned inc0 = inc1 + h0;
            const unsigned rem = sh_rem;
            int cand = -1; unsigned candExcl = 0;
            if      (inc3 >= rem) { cand = 4 * t + 3; candExcl = exclc; }
            else if (inc2 >= rem) { cand = 4 * t + 2; candExcl = inc3; }
            else if (inc1 >= rem) { cand = 4 * t + 1; candExcl = inc2; }
            else if (inc0 >= rem) { cand = 4 * t + 0; candExcl = inc1; }
#pragma unroll
            for (int off = 32; off > 0; off >>= 1) {
                int c2 = __shfl_down(cand, off);
                unsigned p2 = __shfl_down(candExcl, off);
                if (c2 > cand) { cand = c2; candExcl = p2; }
            }
            if (t == 0) {
                sh_prefix = pre | ((uint64_t)(unsigned)cand << shift);
                sh_mask = msk | (255ull << shift);
                sh_rem = rem - candExcl;
                sh_binc = hist[cand];
            }
        }
        __syncthreads();
    };

    radix_pass(56, false);
    radix_pass(48, false);

    if (t == 0) sh_cnt = 0;
    __syncthreads();
    const bool compacted = (sh_binc <= 2048u);
    if (compacted) {
        const uint64_t pre = sh_prefix, msk = sh_mask;
        for (int a = t; a < NANCH; a += 1024) {
            uint64_t k = ky[a];
            if ((k & msk) == pre) {
                unsigned p = atomicAdd(&sh_cnt, 1u);
                candk[p] = k; candi[p] = (uint32_t)a;
            }
        }
    }
    __syncthreads();

    for (int pass = 2; pass < 8; pass++)
        radix_pass(56 - 8 * pass, compacted);

    const uint64_t T = sh_prefix;

    sel2[2 * t] = 0; sel2[2 * t + 1] = 0;
    if (t == 0) { sh_cntA = 0; sh_cntB = 0; }
    __syncthreads();
    for (int a = t; a < NANCH; a += 1024) {
        uint64_t k = ky[a];
        if (k > T) {
            unsigned p = atomicAdd(&sh_cntA, 1u);
            sel2[2 * p] = k; sel2[2 * p + 1] = (uint64_t)(~(uint32_t)a);
        }
    }
    __syncthreads();
    const unsigned m = sh_cntA;
    if (compacted) {
        const unsigned nc = sh_cnt;
        for (unsigned j = t; j < nc; j += 1024) {
            if (candk[j] == T) {
                unsigned q = atomicAdd(&sh_cntB, 1u);
                unsigned slot = m + q;
                if (slot < KTOP) { sel2[2 * slot] = T; sel2[2 * slot + 1] = (uint64_t)(~candi[j]); }
            }
        }
    } else {
        for (int a = t; a < NANCH; a += 1024) {
            if (ky[a] == T) {
                unsigned q = atomicAdd(&sh_cntB, 1u);
                unsigned slot = m + q;
                if (slot < KTOP) { sel2[2 * slot] = T; sel2[2 * slot + 1] = (uint64_t)(~(uint32_t)a); }
            }
        }
    }
    __syncthreads();
    {
        const uint64_t myk = sel2[2 * t], myn = sel2[2 * t + 1];
        int rank = 0;
        const ulonglong2* sp = (const ulonglong2*)sel2;
#pragma unroll 8
        for (int j = 0; j < 1024; j++) {
            ulonglong2 v = sp[j];
            rank += (v.x > myk) || (v.x == myk && v.y > myn);
        }
        if (rank < KTOP) { out2[2 * rank] = myk; out2[2 * rank + 1] = myn; }
    }
    __syncthreads();

    if (t < KTOP) {
        uint64_t k = out2[2 * t];
        uint32_t idx = ~(uint32_t)out2[2 * t + 1];
        uint64_t b = (k >> 63) ? (k ^ 0x8000000000000000ull) : ~k;
        double s = __longlong_as_double((long long)b);
        double bx0 = 0.0, bx1 = 0.0, bx2 = 0.0, bx3 = 0.0;
        float sv = (float)s;
        if (idx < NANCH) {
            const double* bp = boxesd + ((size_t)n * NANCH + idx) * 4;
            bx0 = bp[0]; bx1 = bp[1]; bx2 = bp[2]; bx3 = bp[3];
        } else {
            sv = -1.0f;
        }
        double* tp = tbd + ((size_t)n * KTOP + t) * 4;
        tp[0] = bx0; tp[1] = bx1; tp[2] = bx2; tp[3] = bx3;
        topv[n * KTOP + t] = sv;
    }
}

// ---------------------------------------------------------------- K4a: suppression bit-matrix (fp64 IoU) [proven]
__global__ __launch_bounds__(256) void k_supmat(const double* __restrict__ tbd,
                                                uint64_t* __restrict__ sup)
{
    __shared__ double sb[4000];
    const int tile = blockIdx.x, n = blockIdx.y;
    const int t = threadIdx.x;
    for (int i = t; i < 4000; i += 256) sb[i] = tbd[(size_t)n * KTOP * 4 + i];
    __syncthreads();
    const int r0 = tile * 64;
    for (int u = t; u < 1024; u += 256) {
        const int il = u >> 4, wq = u & 15;
        const int i = r0 + il;
        if (i >= 1000) continue;
        const double bix = sb[i * 4], biy = sb[i * 4 + 1], biz = sb[i * 4 + 2], biw = sb[i * 4 + 3];
        const double ai = (biz - bix) * (biw - biy);
        uint64_t bits = 0;
        const int jbase = wq * 64;
        for (int jj = 0; jj < 64; jj++) {
            const int j = jbase + jj;
            if (j < 1000 && j > i) {
                const double bjx = sb[j * 4], bjy = sb[j * 4 + 1], bjz = sb[j * 4 + 2], bjw = sb[j * 4 + 3];
                const double aj = (bjz - bjx) * (bjw - bjy);
                const double ltx = fmax(bix, bjx), lty = fmax(biy, bjy);
                const double rbx = fmin(biz, bjz), rby = fmin(biw, bjw);
                const double ww = fmax(rbx - ltx, 0.0), hh = fmax(rby - lty, 0.0);
                const double inter = ww * hh;
                const double iou = inter / (ai + aj - inter + 1e-8);
                if (iou > 0.7) bits |= (1ull << jj);
            }
        }
        sup[((size_t)n * KTOP + i) * 16 + wq] = bits;
    }
}

// ---------------------------------------------------------------- K4b: sequential NMS scan (1 wave/img) [proven]
__global__ __launch_bounds__(64) void k_nms(const uint64_t* __restrict__ sup,
                                            uint64_t* __restrict__ keepout)
{
    const int n = blockIdx.x;
    const int lane = threadIdx.x;
    const uint64_t* rows = sup + (size_t)n * KTOP * 16;

    uint64_t keep;
    if (lane < 15) keep = ~0ull;
    else if (lane == 15) keep = (1ull << 40) - 1;
    else keep = 0;

    uint64_t A[8], B[8];
    auto LOADG = [&](uint64_t* dst, int g) {
#pragma unroll
        for (int k = 0; k < 8; k++) {
            int i = g * 8 + k;
            dst[k] = (lane < 16) ? rows[(size_t)i * 16 + lane] : 0ull;
        }
    };
    auto PROCG = [&](const uint64_t* src, int g) {
#pragma unroll
        for (int k = 0; k < 8; k++) {
            int i = g * 8 + k;
            uint64_t kw = __shfl(keep, i >> 6);
            bool alive = (kw >> (i & 63)) & 1ull;
            keep &= alive ? ~src[k] : ~0ull;
        }
    };

    LOADG(A, 0);
    for (int g = 0; g < 125; g += 2) {
        if (g + 1 < 125) LOADG(B, g + 1);
        PROCG(A, g);
        if (g + 2 < 125) LOADG(A, g + 2);
        if (g + 1 < 125) PROCG(B, g + 1);
    }
    if (lane < 16) keepout[n * 16 + lane] = keep;
}

// ---------------------------------------------------------------- K5: stable compaction + output [proven]
__global__ __launch_bounds__(1024) void k_final(const uint64_t* __restrict__ keepw,
                                                const float* __restrict__ topv,
                                                const double* __restrict__ tbd,
                                                float* __restrict__ out)
{
    __shared__ int sc[1024];
    __shared__ uint64_t kw[16];
    __shared__ int sh_total;
    const int n = blockIdx.x, t = threadIdx.x;
    if (t < 16) kw[t] = keepw[n * 16 + t];
    __syncthreads();

    int val = 0;
    bool kept = false;
    if (t < 1000) {
        bool bit = (kw[t >> 6] >> (t & 63)) & 1ull;
        float v = topv[n * KTOP + t];
        kept = bit && (v > 0.0f);
        val = kept ? 1 : 0;
    }
    sc[t] = val;
    __syncthreads();
    for (int off = 1; off < 1024; off <<= 1) {
        int x = (t >= off) ? sc[t - off] : 0;
        __syncthreads();
        sc[t] += x;
        __syncthreads();
    }
    if (t == 1023) sh_total = sc[1023];
    __syncthreads();
    const int total = sh_total;
    if (t < 1000) {
        if (kept) {
            int r = sc[t] - 1;
            const double* bp = tbd + ((size_t)n * KTOP + t) * 4;
            float* o = out + ((size_t)n * KTOP + r) * 5;
            o[0] = (float)bp[0]; o[1] = (float)bp[1];
            o[2] = (float)bp[2]; o[3] = (float)bp[3];
            o[4] = (float)n;
        }
        if (t >= total) {
            float* o = out + ((size_t)n * KTOP + t) * 5;
            o[0] = 0.0f; o[1] = 0.0f; o[2] = 0.0f; o[3] = 0.0f; o[4] = (float)n;
        }
    }
}

// ---------------------------------------------------------------- legacy fallback conv + heads (R8 proven)
__global__ __launch_bounds__(128) void k_conv3_full(const float* __restrict__ in,
                                                    const float* __restrict__ w,
                                                    const float* __restrict__ bias,
                                                    float* __restrict__ out)
{
    __shared__ double ind[2][672];
    const int tile = blockIdx.x, ocg = blockIdx.y, n = blockIdx.z;
    const int ty = tile / 5, tx = tile % 5;
    const int y0 = ty * 5, x0 = tx * 10;
    const int t = threadIdx.x;
    const int oc_l = t & 63;
    const int g = t >> 6;
    const int base_lx = g * 5;
    const int oc0 = ocg * 64;

    int soff[6];
#pragma unroll
    for (int k = 0; k < 6; k++) {
        int idx = t + k * 128;
        soff[k] = -1;
        if (idx < 672) {
            int c = idx / 84, rem = idx - c * 84;
            int iy = rem / 12, ix = rem - iy * 12;
            int y = y0 - 1 + iy, x = x0 - 1 + ix;
            if ((unsigned)y < 50u && (unsigned)x < 50u)
                soff[k] = (n * CIN + c) * SPAT + y * FW + x;
        }
    }
    const float* wrow = w + (size_t)(oc0 + oc_l) * (CIN * 9);
    double acc[5][5];
#pragma unroll
    for (int i = 0; i < 5; i++)
#pragma unroll
        for (int j = 0; j < 5; j++) acc[i][j] = 0.0;
    float rin[6];
#pragma unroll
    for (int k = 0; k < 6; k++) rin[k] = (soff[k] >= 0) ? in[soff[k]] : 0.0f;
    float wnxt[9];
#pragma unroll
    for (int k = 0; k < 9; k++) wnxt[k] = wrow[k];

    for (int cc = 0; cc < 64; ++cc) {
        const int cur = cc & 1;
#pragma unroll
        for (int k = 0; k < 6; k++) {
            int idx = t + k * 128;
            if (idx < 672) ind[cur][idx] = (double)rin[k];
        }
        __syncthreads();
        if (cc < 63) {
            const int coff = (cc + 1) * (8 * SPAT);
#pragma unroll
            for (int k = 0; k < 6; k++)
                rin[k] = (soff[k] >= 0) ? in[soff[k] + coff] : 0.0f;
        }
#pragma unroll 1
        for (int c = 0; c < 8; c++) {
            double wd[9];
#pragma unroll
            for (int k = 0; k < 9; k++) wd[k] = (double)wnxt[k];
            const int nidx = cc * 8 + c + 1;
            if (nidx < 512) {
                const float* wp = wrow + nidx * 9;
#pragma unroll
                for (int k = 0; k < 9; k++) wnxt[k] = wp[k];
            }
#pragma unroll
            for (int r = 0; r < 7; r++) {
                double drow[7];
#pragma unroll
                for (int j = 0; j < 7; j++)
                    drow[j] = ind[cur][c * 84 + r * 12 + base_lx + j];
#pragma unroll
                for (int dy = 0; dy < 3; dy++) {
                    const int iy = r - dy;
                    if (iy >= 0 && iy < 5) {
#pragma unroll
                        for (int dx = 0; dx < 3; dx++) {
                            const double wdv = wd[dy * 3 + dx];
#pragma unroll
                            for (int ix = 0; ix < 5; ix++)
                                acc[iy][ix] = fma(wdv, drow[ix + dx], acc[iy][ix]);
                        }
                    }
                }
            }
        }
        __syncthreads();
    }
    const double b = (double)bias[oc0 + oc_l];
#pragma unroll
    for (int iy = 0; iy < 5; iy++)
#pragma unroll
        for (int ix = 0; ix < 5; ix++) {
            int y = y0 + iy, x = x0 + base_lx + ix;
            out[(n * COUT + oc0 + oc_l) * SPAT + y * FW + x] = (float)(acc[iy][ix] + b);
        }
}

__global__ __launch_bounds__(256) void k_heads_legacy(const float* __restrict__ conv1,
                                                      const float* __restrict__ cls_w,
                                                      const float* __restrict__ cls_b,
                                                      const float* __restrict__ bbox_w,
                                                      const float* __restrict__ bbox_b,
                                                      double* __restrict__ boxesd,
                                                      double* __restrict__ scored)
{
    __shared__ float feat[25 * 257];
    __shared__ double outb[54 * 25];
    const int blk = blockIdx.x, n = blockIdx.y;
    const int pos0 = blk * 25;
    const int t = threadIdx.x;

    for (int idx = t; idx < 6400; idx += 256) {
        int c = idx / 25, p = idx - c * 25;
        feat[p * 257 + c] = conv1[(n * COUT + c) * SPAT + pos0 + p];
    }
    __syncthreads();
    for (int u = t; u < 1350; u += 256) {
        const int oc = u % 54, p = u / 54;
        const float* wp = (oc < 18) ? (cls_w + oc * COUT) : (bbox_w + (oc - 18) * COUT);
        double s = (double)((oc < 18) ? cls_b[oc] : bbox_b[oc - 18]);
        const float* fp = &feat[p * 257];
#pragma unroll 8
        for (int c = 0; c < COUT; c++) s = fma((double)wp[c], (double)fp[c], s);
        outb[oc * 25 + p] = s;
    }
    __syncthreads();
    if (t < 225) {
        const int p = t / 9, k = t - p * 9;
        const int pos = pos0 + p;
        const int y = pos / 50, x = pos - y * 50;
        const int ri = k / 3, si = k - ri * 3;
        const double ratio = (ri == 0) ? 0.5 : ((ri == 1) ? 1.0 : 2.0);
        const double size = (si == 0) ? 128.0 : ((si == 1) ? 256.0 : 512.0);
        const double hr = sqrt(ratio), wr = 1.0 / hr;
        const double wsz = wr * size, hsz = hr * size;
        const double bx0 = rint(-wsz * 0.5), by0 = rint(-hsz * 0.5);
        const double bx1 = rint(wsz * 0.5), by1 = rint(hsz * 0.5);
        const double sxf = (double)(x * 16), syf = (double)(y * 16);
        const double a0 = sxf + bx0, a1 = syf + by0, a2 = sxf + bx1, a3 = syf + by1;
        const double aw = a2 - a0, ah = a3 - a1;
        const double cx = a0 + 0.5 * aw, cy = a1 + 0.5 * ah;
        const double d0 = outb[(18 + k * 4 + 0) * 25 + p];
        const double d1 = outb[(18 + k * 4 + 1) * 25 + p];
        const double d2 = outb[(18 + k * 4 + 2) * 25 + p];
        const double d3 = outb[(18 + k * 4 + 3) * 25 + p];
        const double ncx = d0 * aw + cx, ncy = d1 * ah + cy;
        const double nw = exp(d2) * aw, nh = exp(d3) * ah;
        double x1 = ncx - 0.5 * nw, y1 = ncy - 0.5 * nh;
        double x2 = ncx + 0.5 * nw, y2 = ncy + 0.5 * nh;
        x1 = fmin(fmax(x1, 0.0), 800.0);
        y1 = fmin(fmax(y1, 0.0), 800.0);
        x2 = fmin(fmax(x2, 0.0), 800.0);
        y2 = fmin(fmax(y2, 0.0), 800.0);
        double* bp = boxesd + ((size_t)n * NANCH + pos * 9 + k) * 4;
        bp[0] = x1; bp[1] = y1; bp[2] = x2; bp[3] = y2;
    }
    for (int u = t; u < 450; u += 256) {
        const int ch = u / 25, p = u - ch * 25;
        const int pos = pos0 + p;
        if (pos & 1) {
            const int a = ch * 1250 + ((pos - 1) >> 1);
            const double v = outb[ch * 25 + p];
            scored[(size_t)n * NANCH + a] = 1.0 / (1.0 + exp(-v));
        }
    }
}

// ---------------------------------------------------------------- launch
extern "C" void kernel_launch(void* const* d_in, const int* in_sizes, int n_in,
                              void* d_out, int out_size, void* d_ws, size_t ws_size,
                              hipStream_t stream)
{
    (void)in_sizes; (void)n_in; (void)out_size;
    const float* feat   = (const float*)d_in[1];
    const float* conv_w = (const float*)d_in[2];
    const float* conv_b = (const float*)d_in[3];
    const float* cls_w  = (const float*)d_in[4];
    const float* cls_b  = (const float*)d_in[5];
    const float* bbox_w = (const float*)d_in[6];
    const float* bbox_b = (const float*)d_in[7];
    float* out = (float*)d_out;
    char* ws = (char*)d_ws;

    const size_t PB   = 40960000ull;
    const size_t REST = 5760000 + 1440000 + 1440000 + 256000 + 32000 + 1024000 + 1024;

    int S = 0;
    if      (ws_size >= 4 * PB + REST) S = 4;
    else if (ws_size >= 2 * PB + REST) S = 2;
    else if (ws_size >= 1 * PB + REST) S = 1;

    if (S > 0) {
        double*   parts  = (double*)ws;
        char*     p      = ws + (size_t)S * PB;
        double*   boxesd = (double*)(p);               p += 5760000;
        double*   scored = (double*)(p);               p += 1440000;
        uint64_t* keys   = (uint64_t*)(p);             p += 1440000;
        double*   tbd    = (double*)(p);               p += 256000;
        float*    topv   = (float*)(p);                p += 32000;
        uint64_t* sup    = (uint64_t*)(p);             p += 1024000;
        uint64_t* keepw  = (uint64_t*)(p);

        k_conv3_part <<<dim3(25, 4, 8 * S), 256, 0, stream>>>(feat, conv_w, parts, S);
        k_heads_fused<<<dim3(100, 8), 256, 0, stream>>>(parts, S, conv_b, cls_w, cls_b,
                                                        bbox_w, bbox_b, boxesd, scored);
        k_keys  <<<dim3(88, 8), 256, 0, stream>>>(boxesd, scored, keys);
        k_select<<<8, 1024, 0, stream>>>(boxesd, keys, tbd, topv);
        k_supmat<<<dim3(16, 8), 256, 0, stream>>>(tbd, sup);
        k_nms   <<<8, 64, 0, stream>>>(sup, keepw);
        k_final <<<8, 1024, 0, stream>>>(keepw, topv, tbd, out);
    } else {
        float*    conv1  = (float*)(ws);
        double*   boxesd = (double*)(ws + 20480000);
        double*   scored = (double*)(ws + 26240000);
        uint64_t* keys   = (uint64_t*)(ws + 27680000);
        double*   tbd    = (double*)(ws + 29120000);
        float*    topv   = (float*)(ws + 29376000);
        uint64_t* sup    = (uint64_t*)(ws + 29408000);
        uint64_t* keepw  = (uint64_t*)(ws + 30432000);

        k_conv3_full  <<<dim3(50, 4, 8), 128, 0, stream>>>(feat, conv_w, conv_b, conv1);
        k_heads_legacy<<<dim3(100, 8), 256, 0, stream>>>(conv1, cls_w, cls_b, bbox_w, bbox_b, boxesd, scored);
        k_keys  <<<dim3(88, 8), 256, 0, stream>>>(boxesd, scored, keys);
        k_select<<<8, 1024, 0, stream>>>(boxesd, keys, tbd, topv);
        k_supmat<<<dim3(16, 8), 256, 0, stream>>>(tbd, sup);
        k_nms   <<<8, 64, 0, stream>>>(sup, keepw);
        k_final <<<8, 1024, 0, stream>>>(keepw, topv, tbd, out);
    }
}